// Round 8
// baseline (127.388 us; speedup 1.0000x reference)
//
#include <hip/hip_runtime.h>

// QueryAndGroup: ball_query(r=0.2, ns=32) + group xyz (centered) + group features.
//   xyz      [8][16384][3] f32   d_in[0]
//   new_xyz  [8][1024][3]  f32   d_in[1]
//   features [8][64][16384] f32  d_in[2]
//   out      [8][67][1024][32] f32
//
// Ledger: R7 f4-vectorize -6 (best 120.4). R8 staging 0. R9 DMA +1.
// R10 coop-scan +13 (proves kernel time passes through). R11 wide-scan 0.
// R12 (this round): structural fusion. K1 = transpose tile + ball-query
// phase-1 in ONE kernel (parity-ordered so mem-bound transpose overlaps
// compute-bound query across co-resident blocks); slots -> ws. K2 = pure
// gather/store. SoA arrays eliminated: 256-pt AoS chunk = 3072 contiguous
// bytes = 3 coalesced f4/lane, unpacked in-register (same VMEM count and
// lane->point mapping as SoA).

#define N_PTS   16384
#define M_Q     1024
#define B_SZ    8
#define NSAMP   32
#define NCH     64
#define R2      0.04f
#define OUT_CH  (3 + NCH)

typedef float f4 __attribute__((ext_vector_type(4)));

// ==================== K1: fused transpose + ball-query ====================
__global__ __launch_bounds__(256, 8) void k1_transpose_query(
    const float* __restrict__ xyz,      // [B][N][3]
    const float* __restrict__ new_xyz,  // [B][M][3]
    const float* __restrict__ feat,     // [B][C][N]
    float* __restrict__ ft,             // [B][N][C]  (ws)
    float* __restrict__ pslots)         // [B*M][NSAMP][4] = {x,y,z,idxbits} (ws)
{
    const int tid = threadIdx.x;
    const int b   = blockIdx.x & 7;                // XCD swizzle: batch
    const int g   = blockIdx.x >> 3;               // 0..255: tile group / query group

    __shared__ float tile[64][65];                 // transpose staging (+1 pad)
    __shared__ float pxyz[4][NSAMP][4];            // per-wave slot buffer

    // ---- role A: transpose one 64x64 feature tile ----
    auto do_transpose = [&]() {
        const int n0 = g << 6;
        const float* __restrict__ fb = feat + (size_t)b * NCH * N_PTS;
        float* __restrict__ tb       = ft   + ((size_t)b * N_PTS + n0) * NCH;
#pragma unroll
        for (int j = 0; j < 4; ++j) {
            const int fidx = j * 256 + tid;
            const int c = fidx >> 4, qq = fidx & 15;
            const f4 v = __builtin_nontemporal_load(
                (const f4*)&fb[(size_t)c * N_PTS + n0 + qq * 4]);
            tile[c][qq * 4 + 0] = v.x;
            tile[c][qq * 4 + 1] = v.y;
            tile[c][qq * 4 + 2] = v.z;
            tile[c][qq * 4 + 3] = v.w;
        }
        __syncthreads();
        const int c4 = tid & 15;
        const int r  = tid >> 4;
#pragma unroll
        for (int j = 0; j < 4; ++j) {              // 1KB dwordx4 per instr
            const int nn = j * 16 + r;
            f4 o;
            o.x = tile[c4 * 4 + 0][nn];
            o.y = tile[c4 * 4 + 1][nn];
            o.z = tile[c4 * 4 + 2][nn];
            o.w = tile[c4 * 4 + 3][nn];
            *(f4*)(&tb[(size_t)nn * NCH + c4 * 4]) = o;  // re-read in K2: keep cached
        }
    };

    // ---- role B: ordered ball query for 4 queries (one per wave) ----
    auto do_query = [&]() {
        const int w    = tid >> 6;
        const int lane = tid & 63;
        const int m    = (g << 2) + w;
        const int q    = (b << 10) + m;

        const float cx = new_xyz[q * 3 + 0];
        const float cy = new_xyz[q * 3 + 1];
        const float cz = new_xyz[q * 3 + 2];
        const float* __restrict__ xb = xyz + (size_t)b * N_PTS * 3;
        const unsigned long long lmask = (1ull << lane) - 1ull;
        int cnt = 0;

        // AoS f4 scan: chunk of 256 pts = 3072 contiguous bytes; lane l
        // reads 3 f4 at float-offset base*3 + l*12 + {0,4,8} -> pts 4l..4l+3.
        f4 L0 = *(const f4*)(xb + lane * 12);
        f4 L1 = *(const f4*)(xb + lane * 12 + 4);
        f4 L2 = *(const f4*)(xb + lane * 12 + 8);

        for (int base = 0; ; base += 256) {
            // prefetch next chunk before this iteration's ballots
            const int  nbase = base + 256;
            const bool more  = nbase < N_PTS;
            const int  fo    = (more ? nbase * 3 : 0) + lane * 12;  // dummy: L1 hit
            const f4 NL0 = *(const f4*)(xb + fo);
            const f4 NL1 = *(const f4*)(xb + fo + 4);
            const f4 NL2 = *(const f4*)(xb + fo + 8);

            const float X[4] = {L0.x, L0.w, L1.z, L2.y};
            const float Y[4] = {L0.y, L1.x, L1.w, L2.z};
            const float Z[4] = {L0.z, L1.y, L2.x, L2.w};

            float d2k[4];
#pragma unroll
            for (int k = 0; k < 4; ++k) {
                const float dx = __fsub_rn(cx, X[k]);
                const float dy = __fsub_rn(cy, Y[k]);
                const float dz = __fsub_rn(cz, Z[k]);
                d2k[k] = __fadd_rn(__fadd_rn(__fmul_rn(dx, dx), __fmul_rn(dy, dy)),
                                   __fmul_rn(dz, dz));
            }
            const bool h0 = d2k[0] < R2, h1 = d2k[1] < R2;
            const bool h2 = d2k[2] < R2, h3 = d2k[3] < R2;
            const unsigned long long m0 = __ballot(h0);
            const unsigned long long m1 = __ballot(h1);
            const unsigned long long m2 = __ballot(h2);
            const unsigned long long m3 = __ballot(h3);

            const int P = (int)(__popcll(m0 & lmask) + __popcll(m1 & lmask) +
                                __popcll(m2 & lmask) + __popcll(m3 & lmask));
            int own = 0;
            const bool hk[4] = {h0, h1, h2, h3};
#pragma unroll
            for (int k = 0; k < 4; ++k) {
                if (hk[k]) {
                    const int slot = cnt + P + own;
                    if (slot < NSAMP) {
                        pxyz[w][slot][0] = X[k];
                        pxyz[w][slot][1] = Y[k];
                        pxyz[w][slot][2] = Z[k];
                        pxyz[w][slot][3] = __int_as_float(base + lane * 4 + k);
                    }
                }
                own += hk[k] ? 1 : 0;
            }
            cnt += (int)(__popcll(m0) + __popcll(m1) + __popcll(m2) + __popcll(m3));

            if (cnt >= NSAMP || !more) break;
            L0 = NL0; L1 = NL1; L2 = NL2;
        }

        // fill empty slots with slot 0 (reference broadcasts sorted_idx[...,0])
        if (lane < NSAMP && cnt < NSAMP) {
            float v0x, v0y, v0z, v0w;
            if (cnt > 0) {
                v0x = pxyz[w][0][0]; v0y = pxyz[w][0][1];
                v0z = pxyz[w][0][2]; v0w = pxyz[w][0][3];
            } else {
                v0x = xb[0]; v0y = xb[1]; v0z = xb[2]; v0w = __int_as_float(0);
            }
            if (lane >= cnt) {
                pxyz[w][lane][0] = v0x; pxyz[w][lane][1] = v0y;
                pxyz[w][lane][2] = v0z; pxyz[w][lane][3] = v0w;
            }
        }
        // wave-synchronous LDS; dump 512B/wave coalesced to ws
        if (lane < NSAMP) {
            *(f4*)&pslots[((size_t)q * NSAMP + lane) * 4] =
                *(const f4*)&pxyz[w][lane][0];
        }
    };

    // parity-ordered roles: co-resident blocks mix mem-bound + compute-bound
    if (blockIdx.x & 1) { do_query(); do_transpose(); }
    else                { do_transpose(); do_query(); }
}

// ==================== K2: gather + store ====================
__global__ __launch_bounds__(256, 8) void k2_gather(
    const float* __restrict__ new_xyz,  // [B][M][3]
    const float* __restrict__ ft,       // [B][N][C]
    const float* __restrict__ pslots,   // [B*M][NSAMP][4]
    float* __restrict__ out)            // [B][67][M][NS]
{
    const int tid  = threadIdx.x;
    const int w    = tid >> 6;
    const int lane = tid & 63;
    const int b    = blockIdx.x & 7;               // XCD swizzle
    const int m    = ((blockIdx.x >> 3) << 2) + w;
    const int q    = (b << 10) + m;

    __shared__ float pxyz[4][NSAMP][4];
    __shared__ float tile[4][32][33];

    if (lane < NSAMP) {
        *(f4*)&pxyz[w][lane][0] = *(const f4*)&pslots[((size_t)q * NSAMP + lane) * 4];
    }
    // same-wave ds_write -> ds_read ordered by lgkmcnt (no barrier needed)

    const float cx = new_xyz[q * 3 + 0];
    const float cy = new_xyz[q * 3 + 1];
    const float cz = new_xyz[q * 3 + 2];
    float* __restrict__ ob = out + ((size_t)b * OUT_CH * M_Q + (size_t)m) * NSAMP;

    // ---- Phase 2a: centered xyz channels (24 lanes, 1 dwordx4) ----
    if (lane < 24) {
        const int c  = lane >> 3;        // 0..2
        const int s4 = lane & 7;
        const float ctr = (c == 0) ? cx : ((c == 1) ? cy : cz);
        f4 o;
        o.x = __fsub_rn(pxyz[w][s4 * 4 + 0][c], ctr);
        o.y = __fsub_rn(pxyz[w][s4 * 4 + 1][c], ctr);
        o.z = __fsub_rn(pxyz[w][s4 * 4 + 2][c], ctr);
        o.w = __fsub_rn(pxyz[w][s4 * 4 + 3][c], ctr);
        __builtin_nontemporal_store(o, (f4*)&ob[(size_t)c * (M_Q * NSAMP) + s4 * 4]);
    }

    // ---- Phase 2b: feature rows (256B contiguous), LDS transpose, nt stores ----
    const float* __restrict__ ftb = ft;  // offset below includes batch via n? no:
    const float* __restrict__ ftbb = ft; // (kept simple: index with batch base)
    const float* __restrict__ fb = ft + (size_t)b * N_PTS * NCH;
    const int sgrp = lane >> 3;          // 0..7
    const int c4   = lane & 7;           // float4 within 32-ch chunk
    (void)ftb; (void)ftbb;

#pragma unroll
    for (int chunk = 0; chunk < 2; ++chunk) {
        f4 vals[4];
#pragma unroll
        for (int i = 0; i < 4; ++i) {    // 8 lanes x 128B per row-half
            const int s = i * 8 + sgrp;
            const int n = __float_as_int(pxyz[w][s][3]);
            vals[i] = *(const f4*)(fb + (size_t)n * NCH + chunk * 32 + c4 * 4);
        }
#pragma unroll
        for (int i = 0; i < 4; ++i) {    // [s][c] -> [c][s]  (<=2-way banks: free)
            const int s = i * 8 + sgrp;
            tile[w][c4 * 4 + 0][s] = vals[i].x;
            tile[w][c4 * 4 + 1][s] = vals[i].y;
            tile[w][c4 * 4 + 2][s] = vals[i].z;
            tile[w][c4 * 4 + 3][s] = vals[i].w;
        }
#pragma unroll
        for (int j = 0; j < 4; ++j) {    // 1KB nt store per instr
            const int c_loc = j * 8 + (lane >> 3);
            const int s4    = lane & 7;
            f4 o;
            o.x = tile[w][c_loc][s4 * 4 + 0];
            o.y = tile[w][c_loc][s4 * 4 + 1];
            o.z = tile[w][c_loc][s4 * 4 + 2];
            o.w = tile[w][c_loc][s4 * 4 + 3];
            __builtin_nontemporal_store(
                o, (f4*)&ob[(size_t)(3 + chunk * 32 + c_loc) * (M_Q * NSAMP) + s4 * 4]);
        }
    }
}

// ---------- fallback (ws too small): direct-gather kernel ----------
__global__ __launch_bounds__(256) void qg_fallback(
    const float* __restrict__ xyz, const float* __restrict__ new_xyz,
    const float* __restrict__ feat, float* __restrict__ out)
{
    const int tid  = threadIdx.x;
    const int w    = tid >> 6;
    const int lane = tid & 63;
    const int q    = blockIdx.x * 4 + w;
    const int b    = q >> 10;
    const int m    = q & (M_Q - 1);

    __shared__ int idx_sh[4][NSAMP];

    const float cx = new_xyz[q * 3 + 0];
    const float cy = new_xyz[q * 3 + 1];
    const float cz = new_xyz[q * 3 + 2];
    const float* __restrict__ xb = xyz + (size_t)b * N_PTS * 3;

    int cnt = 0;
    for (int base = 0; base < N_PTS && cnt < NSAMP; base += 64) {
        const int n = base + lane;
        const float dx = __fsub_rn(cx, xb[n * 3 + 0]);
        const float dy = __fsub_rn(cy, xb[n * 3 + 1]);
        const float dz = __fsub_rn(cz, xb[n * 3 + 2]);
        const float d2 = __fadd_rn(__fadd_rn(__fmul_rn(dx, dx), __fmul_rn(dy, dy)),
                                   __fmul_rn(dz, dz));
        const bool hit = d2 < R2;
        const unsigned long long mk = __ballot(hit);
        if (hit) {
            const int slot = cnt + __popcll(mk & ((1ull << lane) - 1ull));
            if (slot < NSAMP) idx_sh[w][slot] = n;
        }
        cnt += (int)__popcll(mk);
    }
    __syncthreads();
    if (lane < NSAMP) {
        const int v0 = (cnt > 0) ? idx_sh[w][0] : 0;
        if (lane >= cnt) idx_sh[w][lane] = v0;
    }
    __syncthreads();

    const float* __restrict__ fb = feat + (size_t)b * NCH * N_PTS;
    float* __restrict__ ob = out + ((size_t)b * OUT_CH * M_Q + (size_t)m) * NSAMP;
    for (int e = lane; e < OUT_CH * NSAMP; e += 64) {
        const int c = e >> 5, s = e & 31;
        const int n = idx_sh[w][s];
        float v;
        if (c < 3) {
            const float ctr = (c == 0) ? cx : ((c == 1) ? cy : cz);
            v = __fsub_rn(xb[n * 3 + c], ctr);
        } else {
            v = fb[(size_t)(c - 3) * N_PTS + n];
        }
        ob[(size_t)c * (M_Q * NSAMP) + s] = v;
    }
}

extern "C" void kernel_launch(void* const* d_in, const int* in_sizes, int n_in,
                              void* d_out, int out_size, void* d_ws, size_t ws_size,
                              hipStream_t stream) {
    const float* xyz     = (const float*)d_in[0];
    const float* new_xyz = (const float*)d_in[1];
    const float* feat    = (const float*)d_in[2];
    float* out           = (float*)d_out;

    const size_t ft_elems   = (size_t)B_SZ * N_PTS * NCH;            // 8388608
    const size_t slot_elems = (size_t)B_SZ * M_Q * NSAMP * 4;        // 1048576
    const size_t need       = (ft_elems + slot_elems) * sizeof(float);  // ~37.7 MB

    float* ft     = (float*)d_ws;
    float* pslots = ft + ft_elems;

    if (ws_size >= need) {
        k1_transpose_query<<<B_SZ * (N_PTS / 64), 256, 0, stream>>>(
            xyz, new_xyz, feat, ft, pslots);
        k2_gather<<<(B_SZ * M_Q) / 4, 256, 0, stream>>>(new_xyz, ft, pslots, out);
    } else {
        qg_fallback<<<(B_SZ * M_Q) / 4, 256, 0, stream>>>(xyz, new_xyz, feat, out);
    }
}